// Round 11
// baseline (703.911 us; speedup 1.0000x reference)
//
#include <hip/hip_runtime.h>
#include <hip/hip_bf16.h>

#define B_ 256
#define T_ 512
#define IN_ 202
#define HID_ 100
#define K_ 19

typedef __attribute__((ext_vector_type(8))) short short8v;
typedef __attribute__((ext_vector_type(4))) float f32x4;

__device__ __forceinline__ float rl_f(float v, int l) {
  return __int_as_float(__builtin_amdgcn_readlane(__float_as_int(v), l));
}

// ---------------- K0: split [wf;wb] (200x202) into 3 exact bf16 planes, padded to 224x224.
__global__ __launch_bounds__(256, 1) void k_wprep(
    const float* __restrict__ wf, const float* __restrict__ wb,
    unsigned short* __restrict__ w3) {
  int idx = blockIdx.x * 256 + threadIdx.x;
  if (idx >= 224 * 224) return;
  int c = idx / 224, k = idx - (idx / 224) * 224;
  float v = 0.f;
  if (k < IN_) {
    if (c < 100) v = wf[c * IN_ + k];
    else if (c < 200) v = wb[(c - 100) * IN_ + k];
  }
  unsigned u0 = __float_as_uint(v) & 0xffff0000u;
  float r1 = v - __uint_as_float(u0);
  unsigned u1 = __float_as_uint(r1) & 0xffff0000u;
  float r2 = r1 - __uint_as_float(u1);
  w3[idx] = (unsigned short)(u0 >> 16);
  w3[50176 + idx] = (unsigned short)(u1 >> 16);
  w3[100352 + idx] = (unsigned short)(__float_as_uint(r2) >> 16);
}

// ---------------- K1: pre = x . [wf;wb]^T + bias via bf16-split MFMA (round-10 proven).
__global__ __launch_bounds__(256, 2) void k_ih(
    const float* __restrict__ x, const unsigned short* __restrict__ w3,
    const float* __restrict__ bif, const float* __restrict__ bhf,
    const float* __restrict__ bib, const float* __restrict__ bhb,
    float* __restrict__ pre) {
  __shared__ float xs[256 * 36];
  __shared__ float bsum[224];
  int tid = threadIdx.x;
  int wv = tid >> 6, l = tid & 63;
  long row0 = (long)blockIdx.x * 256;
  for (int u = tid; u < 224; u += 256) {
    float bv = 0.f;
    if (u < 100) bv = bif[u] + bhf[u];
    else if (u < 200) bv = bib[u - 100] + bhb[u - 100];
    bsum[u] = bv;
  }
  int lr = l & 15;
  int kq = l >> 4;
  for (int g = 0; g < 2; g++) {
    f32x4 acc[4][7];
#pragma unroll
    for (int m = 0; m < 4; m++)
#pragma unroll
      for (int n = 0; n < 7; n++) acc[m][n] = (f32x4){0.f, 0.f, 0.f, 0.f};
    for (int ck = 0; ck < 7; ck++) {
      int k0 = ck * 32;
      __syncthreads();
#pragma unroll
      for (int i = 0; i < 16; i++) {
        int u = tid + i * 256;
        int r = u >> 4, kp = u & 15;
        int gk = k0 + 2 * kp;
        float2 v = make_float2(0.f, 0.f);
        if (gk < IN_) v = *(const float2*)(x + (row0 + r) * IN_ + gk);
        *(float2*)(&xs[r * 36 + 2 * kp]) = v;
      }
      __syncthreads();
      short8v A0[4], A1[4], A2[4];
#pragma unroll
      for (int m = 0; m < 4; m++) {
        const float* ap = &xs[(wv * 64 + m * 16 + lr) * 36 + kq * 8];
        float4 fa = *(const float4*)(ap);
        float4 fb = *(const float4*)(ap + 4);
        float f[8] = {fa.x, fa.y, fa.z, fa.w, fb.x, fb.y, fb.z, fb.w};
#pragma unroll
        for (int j = 0; j < 8; j++) {
          unsigned u0 = __float_as_uint(f[j]) & 0xffff0000u;
          float r1 = f[j] - __uint_as_float(u0);
          unsigned u1 = __float_as_uint(r1) & 0xffff0000u;
          float r2 = r1 - __uint_as_float(u1);
          A0[m][j] = (short)(u0 >> 16);
          A1[m][j] = (short)(u1 >> 16);
          A2[m][j] = (short)(__float_as_uint(r2) >> 16);
        }
      }
#pragma unroll
      for (int n = 0; n < 7; n++) {
        int col = (g * 7 + n) * 16 + lr;
        const unsigned short* bp = w3 + (long)col * 224 + k0 + kq * 8;
        short8v B0 = *(const short8v*)(bp);
        short8v B1 = *(const short8v*)(bp + 50176);
        short8v B2 = *(const short8v*)(bp + 100352);
#pragma unroll
        for (int m = 0; m < 4; m++) {
          f32x4 c = acc[m][n];
          c = __builtin_amdgcn_mfma_f32_16x16x32_bf16(A0[m], B0, c, 0, 0, 0);
          c = __builtin_amdgcn_mfma_f32_16x16x32_bf16(A0[m], B1, c, 0, 0, 0);
          c = __builtin_amdgcn_mfma_f32_16x16x32_bf16(A1[m], B0, c, 0, 0, 0);
          c = __builtin_amdgcn_mfma_f32_16x16x32_bf16(A0[m], B2, c, 0, 0, 0);
          c = __builtin_amdgcn_mfma_f32_16x16x32_bf16(A2[m], B0, c, 0, 0, 0);
          c = __builtin_amdgcn_mfma_f32_16x16x32_bf16(A1[m], B1, c, 0, 0, 0);
          c = __builtin_amdgcn_mfma_f32_16x16x32_bf16(A1[m], B2, c, 0, 0, 0);
          c = __builtin_amdgcn_mfma_f32_16x16x32_bf16(A2[m], B1, c, 0, 0, 0);
          acc[m][n] = c;
        }
      }
    }
#pragma unroll
    for (int m = 0; m < 4; m++) {
      long rbase = row0 + wv * 64 + m * 16 + kq * 4;
#pragma unroll
      for (int n = 0; n < 7; n++) {
        int col = (g * 7 + n) * 16 + lr;
        if (col < 200) {
          float bv = bsum[col];
#pragma unroll
          for (int r = 0; r < 4; r++)
            pre[(rbase + r) * 200 + col] = acc[m][n][r] + bv;
        }
      }
    }
  }
}

// ---------------- K2: recurrence over b (256 steps); 4 waves per (t,dir) chain (round-5 proven).
template <int KO, int KN, bool OW>
__device__ __forceinline__ void rnn_loop(
    float* __restrict__ p, long step, int row, bool owns,
    const float* __restrict__ w, float (*hb)[104], float* __restrict__ ps) {
  float wr[KN];
#pragma unroll
  for (int i = 0; i < KN / 4; i++) {
    float4 w4 = *(const float4*)(w + row * HID_ + KO + 4 * i);
    wr[4 * i + 0] = w4.x; wr[4 * i + 1] = w4.y;
    wr[4 * i + 2] = w4.z; wr[4 * i + 3] = w4.w;
  }
  float a = 0.f;
  if (OW) a = p[row];
  for (int s = 0; s < B_; s++) {
    int cur = s & 1;
    float a_next = 0.f;
    if (OW && s < B_ - 1) a_next = p[step + row];
    float ac0 = OW ? a : 0.f, ac1 = 0.f, ac2 = 0.f, ac3 = 0.f;
#pragma unroll
    for (int i = 0; i < KN / 4; i++) {
      float4 h4 = *(const float4*)(&hb[cur][KO + 4 * i]);
      ac0 = fmaf(h4.x, wr[4 * i + 0], ac0);
      ac1 = fmaf(h4.y, wr[4 * i + 1], ac1);
      ac2 = fmaf(h4.z, wr[4 * i + 2], ac2);
      ac3 = fmaf(h4.w, wr[4 * i + 3], ac3);
    }
    float partial = (ac0 + ac1) + (ac2 + ac3);
    if (!OW && owns) ps[row] = partial;
    __syncthreads();
    if (OW) {
      float hnew = tanhf(partial + ps[row]);
      if (owns) {
        hb[cur ^ 1][row] = hnew;
        p[row] = hnew;
      }
    }
    p += step;
    a = a_next;
    __syncthreads();
  }
}

__global__ __launch_bounds__(256, 4) void k_rnn(
    float* __restrict__ pre,
    const float* __restrict__ whf, const float* __restrict__ whb) {
  __shared__ float hb[2][104];
  __shared__ float ps[104];
  int bid = blockIdx.x;
  int dir = bid >> 9;
  int t = bid & 511;
  const float* w = dir ? whb : whf;
  int tid = threadIdx.x;
  int wv = tid >> 6, lane = tid & 63;
  int grp = wv >> 1;
  int khalf = wv & 1;
  int row = grp ? (64 + (lane < 36 ? lane : 35)) : lane;
  bool owns = grp ? (lane < 36) : true;
  long step = dir ? -(long)(T_ * 200) : (long)(T_ * 200);
  float* p = pre + ((long)(dir ? (B_ - 1) : 0) * T_ + t) * 200 + dir * 100;
  if (tid < 104) hb[0][tid] = 0.f;
  __syncthreads();
  if (khalf == 0) rnn_loop<0, 52, true >(p, step, row, owns, w, hb, ps);
  else            rnn_loop<52, 48, false>(p, step, row, owns, w, hb, ps);
}

// ---------------- K3: logits = h @ w_lin^T + b_lin ; softmax over 19. 2 rows/thread.
__global__ __launch_bounds__(256, 4) void k_lin(
    const float* __restrict__ h, const float* __restrict__ wlin,
    const float* __restrict__ blin, float* __restrict__ em) {
  int tid = threadIdx.x;
  long r0 = ((long)blockIdx.x * 256 + tid) * 2;
  const float* h0 = h + r0 * 200;
  float acc0[K_], acc1[K_];
#pragma unroll
  for (int c = 0; c < K_; c++) { float bb = blin[c]; acc0[c] = bb; acc1[c] = bb; }
  for (int kk = 0; kk < 50; kk++) {
    float4 a = *(const float4*)(h0 + 4 * kk);
    float4 b = *(const float4*)(h0 + 200 + 4 * kk);
#pragma unroll
    for (int c = 0; c < K_; c++) {
      float4 wv = *(const float4*)(wlin + c * 200 + 4 * kk);
      acc0[c] += a.x * wv.x + a.y * wv.y + a.z * wv.z + a.w * wv.w;
      acc1[c] += b.x * wv.x + b.y * wv.y + b.z * wv.z + b.w * wv.w;
    }
  }
  float mx0 = acc0[0], mx1 = acc1[0];
#pragma unroll
  for (int c = 1; c < K_; c++) { mx0 = fmaxf(mx0, acc0[c]); mx1 = fmaxf(mx1, acc1[c]); }
  float s0 = 0.f, s1 = 0.f;
#pragma unroll
  for (int c = 0; c < K_; c++) {
    acc0[c] = __expf(acc0[c] - mx0); s0 += acc0[c];
    acc1[c] = __expf(acc1[c] - mx1); s1 += acc1[c];
  }
  float i0 = 1.f / s0, i1 = 1.f / s1;
  float* e0 = em + r0 * K_;
#pragma unroll
  for (int c = 0; c < K_; c++) { e0[c] = acc0[c] * i0; e0[K_ + c] = acc1[c] * i1; }
}

// ---------------- K4: single wave per b. logZ + gold-num + Viterbi fwd fused in one
// instruction stream (two independent dep chains interleave); lane-0-shift logsumexp
// (no per-step shfl reduce); es prefetched one step ahead; truncated at len[b]
// (mask is a prefix); backtrack + direct label writes + last-block loss reduce.
__global__ __launch_bounds__(64, 1) void k_crf(
    const float* __restrict__ em, const int* __restrict__ y,
    const float* __restrict__ st_g, const float* __restrict__ en_g,
    const float* __restrict__ tr_g,
    float* __restrict__ part, int* __restrict__ cnt,
    float* __restrict__ out) {
  __shared__ __align__(16) float es[T_ * K_];
  __shared__ int ys[T_];
  __shared__ float trs[K_ * K_];
  __shared__ float st[K_], en[K_];
  __shared__ unsigned char hl[511 * K_ + 13];
  int b = blockIdx.x;
  int lane = threadIdx.x;
  const float4* eb4 = (const float4*)(em + (long)b * T_ * K_);
  for (int u = lane; u < T_ * K_ / 4; u += 64) ((float4*)es)[u] = eb4[u];
  for (int u = lane; u < T_; u += 64) ys[u] = y[b * T_ + u];
  for (int u = lane; u < K_ * K_; u += 64) trs[u] = tr_g[u];
  if (lane < K_) { st[lane] = st_g[lane]; en[lane] = en_g[lane]; }
  __syncthreads();
  // len = first masked index (mask is a prefix of valid steps)
  int lmin = T_;
  for (int u = lane; u < T_; u += 64)
    if (ys[u] == -1 && u < lmin) lmin = u;
#pragma unroll
  for (int off = 32; off; off >>= 1) {
    int o = __shfl_xor(lmin, off, 64);
    lmin = lmin < o ? lmin : o;
  }
  int len = lmin;  // >= 1

  int jj = lane < K_ ? lane : K_ - 1;
  bool act = lane < K_;
  float E[K_], Tt[K_];
#pragma unroll
  for (int i = 0; i < K_; i++) {
    float tv = trs[i * K_ + jj];
    E[i] = __expf(tv);
    Tt[i] = tv;
  }
  float z = act ? st[jj] + es[jj] : -1e30f;
  float v = z;
  int prev = ys[0];
  float num = st[prev] + es[prev];
  float e = es[K_ + jj];  // t=1 emission (valid even if len==1; unused then)
  for (int t = 1; t < len; t++) {
    int tn = t + 1 < T_ ? t + 1 : T_ - 1;
    float e_next = es[tn * K_ + jj];       // prefetch: off critical path
    int yv = ys[t];
    // ---- logZ chain (lane-0 shift; spread bounded, exp safe)
    float s = rl_f(z, 0);
    float pz = __expf(z - s);
    float acca = 0.f, accb = 0.f;
#pragma unroll
    for (int i = 0; i < 9; i++)  acca = fmaf(rl_f(pz, i), E[i], acca);
#pragma unroll
    for (int i = 9; i < K_; i++) accb = fmaf(rl_f(pz, i), E[i], accb);
    float nz = e + s + __logf(acca + accb);
    // ---- gold-path chain (scalar, same on all lanes)
    num += trs[prev * K_ + yv] + rl_f(e, yv);
    prev = yv;
    // ---- Viterbi chain (absolute scale, exactly like reference)
    float b0 = -1e30f, b1 = -1e30f, b2 = -1e30f, b3 = -1e30f;
    int a0 = 0, a1 = 5, a2 = 10, a3 = 15;
#pragma unroll
    for (int i = 0; i < 5; i++)  { float c = rl_f(v, i) + Tt[i]; if (c > b0) { b0 = c; a0 = i; } }
#pragma unroll
    for (int i = 5; i < 10; i++) { float c = rl_f(v, i) + Tt[i]; if (c > b1) { b1 = c; a1 = i; } }
#pragma unroll
    for (int i = 10; i < 15; i++){ float c = rl_f(v, i) + Tt[i]; if (c > b2) { b2 = c; a2 = i; } }
#pragma unroll
    for (int i = 15; i < 19; i++){ float c = rl_f(v, i) + Tt[i]; if (c > b3) { b3 = c; a3 = i; } }
    if (b1 > b0) { b0 = b1; a0 = a1; }
    if (b2 > b0) { b0 = b2; a0 = a2; }
    if (b3 > b0) { b0 = b3; a0 = a3; }
    if (act) hl[(t - 1) * K_ + lane] = (unsigned char)a0;
    z = act ? nz : z;
    v = act ? b0 + e : v;
    e = e_next;
  }
  num += en[prev];
  // final logsumexp(z + en) (lanes 19..31 hold -1e30 -> 0)
  float zf = act ? z + en[jj] : -1e30f;
  float m2 = zf;
#pragma unroll
  for (int off = 16; off; off >>= 1) m2 = fmaxf(m2, __shfl_xor(m2, off, 32));
  float sm = __expf(zf - m2);
#pragma unroll
  for (int off = 16; off; off >>= 1) sm += __shfl_xor(sm, off, 32);
  if (lane == 0) part[b] = m2 + __logf(sm) - num;
  // final Viterbi argmax (first-max semantics)
  float sc = act ? v + en[jj] : -1e30f;
  float bb = -1e30f; int aa = 0;
#pragma unroll
  for (int i = 0; i < K_; i++) { float c = rl_f(sc, i); if (c > bb) { bb = c; aa = i; } }
  // ---- backtrack + direct label writes
  float* ob = out + 1 + (long)b * T_;
  for (int u = lane; u < T_; u += 64)
    if (u >= len) ob[u] = -1.f;
  int tag = aa;
  if (lane == 0) ob[len - 1] = (float)tag;
  int vc = (act && len >= 2) ? (int)hl[(len - 2) * K_ + lane] : 0;
  for (int ti = len - 2; ti >= 0; ti--) {
    int vn = 0;
    if (ti > 0 && act) vn = (int)hl[(ti - 1) * K_ + lane];
    int ts = __builtin_amdgcn_readfirstlane(tag);
    tag = __builtin_amdgcn_readlane(vc, ts);
    if (lane == 0) ob[ti] = (float)tag;
    vc = vn;
  }
  // ---- deterministic last-block loss reduction
  int old = -1;
  if (lane == 0) { __threadfence(); old = atomicAdd(cnt, 1); }
  old = __shfl(old, 0, 64);
  if (old == B_ - 1) {
    __threadfence();
    float s = 0.f;
    for (int u = lane; u < B_; u += 64) s += part[u];
#pragma unroll
    for (int off = 32; off; off >>= 1) s += __shfl_xor(s, off, 64);
    if (lane == 0) out[0] = s;
  }
}

extern "C" void kernel_launch(void* const* d_in, const int* in_sizes, int n_in,
                              void* d_out, int out_size, void* d_ws, size_t ws_size,
                              hipStream_t stream) {
  const float* x      = (const float*)d_in[0];
  const int*   y      = (const int*)d_in[1];
  const float* w_ih_f = (const float*)d_in[2];
  const float* w_hh_f = (const float*)d_in[3];
  const float* b_ih_f = (const float*)d_in[4];
  const float* b_hh_f = (const float*)d_in[5];
  const float* w_ih_b = (const float*)d_in[6];
  const float* w_hh_b = (const float*)d_in[7];
  const float* b_ih_b = (const float*)d_in[8];
  const float* b_hh_b = (const float*)d_in[9];
  const float* w_lin  = (const float*)d_in[10];
  const float* b_lin  = (const float*)d_in[11];
  const float* st     = (const float*)d_in[12];
  const float* en     = (const float*)d_in[13];
  const float* trans  = (const float*)d_in[14];

  char* ws = (char*)d_ws;
  const size_t PRE_OFF  = 0;                          // 131072*200*4 = 104857600
  const size_t EM_OFF   = 104857600;                  // 131072*19*4  = 9961472
  const size_t PART_OFF = EM_OFF + 9961472;           // 1024
  const size_t CNT_OFF  = PART_OFF + 1024;            // 4
  float* PRE  = (float*)(ws + PRE_OFF);
  float* EM   = (float*)(ws + EM_OFF);
  float* PART = (float*)(ws + PART_OFF);
  int*   CNT  = (int*)(ws + CNT_OFF);
  unsigned short* W3 = (unsigned short*)(ws + EM_OFF);  // consumed before k_lin writes EM
  float* out  = (float*)d_out;

  hipMemsetAsync((void*)CNT, 0, sizeof(int), stream);
  k_wprep<<<196, 256, 0, stream>>>(w_ih_f, w_ih_b, W3);
  k_ih<<<512, 256, 0, stream>>>(x, W3, b_ih_f, b_hh_f, b_ih_b, b_hh_b, PRE);
  k_rnn<<<1024, 256, 0, stream>>>(PRE, w_hh_f, w_hh_b);
  k_lin<<<256, 256, 0, stream>>>(PRE, w_lin, b_lin, EM);
  k_crf<<<256, 64, 0, stream>>>(EM, y, st, en, trans, PART, CNT, out);
}

// Round 12
// 652.305 us; speedup vs baseline: 1.0791x; 1.0791x over previous
//
#include <hip/hip_runtime.h>
#include <hip/hip_bf16.h>

#define B_ 256
#define T_ 512
#define IN_ 202
#define HID_ 100
#define K_ 19

typedef __attribute__((ext_vector_type(8))) short short8v;
typedef __attribute__((ext_vector_type(4))) float f32x4;

__device__ __forceinline__ float rl_f(float v, int l) {
  return __int_as_float(__builtin_amdgcn_readlane(__float_as_int(v), l));
}

// ---------------- K0: split [wf;wb] (200x202) into 3 exact bf16 planes, padded to 224x224.
__global__ __launch_bounds__(256, 1) void k_wprep(
    const float* __restrict__ wf, const float* __restrict__ wb,
    unsigned short* __restrict__ w3) {
  int idx = blockIdx.x * 256 + threadIdx.x;
  if (idx >= 224 * 224) return;
  int c = idx / 224, k = idx - (idx / 224) * 224;
  float v = 0.f;
  if (k < IN_) {
    if (c < 100) v = wf[c * IN_ + k];
    else if (c < 200) v = wb[(c - 100) * IN_ + k];
  }
  unsigned u0 = __float_as_uint(v) & 0xffff0000u;
  float r1 = v - __uint_as_float(u0);
  unsigned u1 = __float_as_uint(r1) & 0xffff0000u;
  float r2 = r1 - __uint_as_float(u1);
  w3[idx] = (unsigned short)(u0 >> 16);
  w3[50176 + idx] = (unsigned short)(u1 >> 16);
  w3[100352 + idx] = (unsigned short)(__float_as_uint(r2) >> 16);
}

// ---------------- K1: pre = x . [wf;wb]^T + bias via bf16-split MFMA (round-10 proven).
__global__ __launch_bounds__(256, 2) void k_ih(
    const float* __restrict__ x, const unsigned short* __restrict__ w3,
    const float* __restrict__ bif, const float* __restrict__ bhf,
    const float* __restrict__ bib, const float* __restrict__ bhb,
    float* __restrict__ pre) {
  __shared__ float xs[256 * 36];
  __shared__ float bsum[224];
  int tid = threadIdx.x;
  int wv = tid >> 6, l = tid & 63;
  long row0 = (long)blockIdx.x * 256;
  for (int u = tid; u < 224; u += 256) {
    float bv = 0.f;
    if (u < 100) bv = bif[u] + bhf[u];
    else if (u < 200) bv = bib[u - 100] + bhb[u - 100];
    bsum[u] = bv;
  }
  int lr = l & 15;
  int kq = l >> 4;
  for (int g = 0; g < 2; g++) {
    f32x4 acc[4][7];
#pragma unroll
    for (int m = 0; m < 4; m++)
#pragma unroll
      for (int n = 0; n < 7; n++) acc[m][n] = (f32x4){0.f, 0.f, 0.f, 0.f};
    for (int ck = 0; ck < 7; ck++) {
      int k0 = ck * 32;
      __syncthreads();
#pragma unroll
      for (int i = 0; i < 16; i++) {
        int u = tid + i * 256;
        int r = u >> 4, kp = u & 15;
        int gk = k0 + 2 * kp;
        float2 v = make_float2(0.f, 0.f);
        if (gk < IN_) v = *(const float2*)(x + (row0 + r) * IN_ + gk);
        *(float2*)(&xs[r * 36 + 2 * kp]) = v;
      }
      __syncthreads();
      short8v A0[4], A1[4], A2[4];
#pragma unroll
      for (int m = 0; m < 4; m++) {
        const float* ap = &xs[(wv * 64 + m * 16 + lr) * 36 + kq * 8];
        float4 fa = *(const float4*)(ap);
        float4 fb = *(const float4*)(ap + 4);
        float f[8] = {fa.x, fa.y, fa.z, fa.w, fb.x, fb.y, fb.z, fb.w};
#pragma unroll
        for (int j = 0; j < 8; j++) {
          unsigned u0 = __float_as_uint(f[j]) & 0xffff0000u;
          float r1 = f[j] - __uint_as_float(u0);
          unsigned u1 = __float_as_uint(r1) & 0xffff0000u;
          float r2 = r1 - __uint_as_float(u1);
          A0[m][j] = (short)(u0 >> 16);
          A1[m][j] = (short)(u1 >> 16);
          A2[m][j] = (short)(__float_as_uint(r2) >> 16);
        }
      }
#pragma unroll
      for (int n = 0; n < 7; n++) {
        int col = (g * 7 + n) * 16 + lr;
        const unsigned short* bp = w3 + (long)col * 224 + k0 + kq * 8;
        short8v B0 = *(const short8v*)(bp);
        short8v B1 = *(const short8v*)(bp + 50176);
        short8v B2 = *(const short8v*)(bp + 100352);
#pragma unroll
        for (int m = 0; m < 4; m++) {
          f32x4 c = acc[m][n];
          c = __builtin_amdgcn_mfma_f32_16x16x32_bf16(A0[m], B0, c, 0, 0, 0);
          c = __builtin_amdgcn_mfma_f32_16x16x32_bf16(A0[m], B1, c, 0, 0, 0);
          c = __builtin_amdgcn_mfma_f32_16x16x32_bf16(A1[m], B0, c, 0, 0, 0);
          c = __builtin_amdgcn_mfma_f32_16x16x32_bf16(A0[m], B2, c, 0, 0, 0);
          c = __builtin_amdgcn_mfma_f32_16x16x32_bf16(A2[m], B0, c, 0, 0, 0);
          c = __builtin_amdgcn_mfma_f32_16x16x32_bf16(A1[m], B1, c, 0, 0, 0);
          c = __builtin_amdgcn_mfma_f32_16x16x32_bf16(A1[m], B2, c, 0, 0, 0);
          c = __builtin_amdgcn_mfma_f32_16x16x32_bf16(A2[m], B1, c, 0, 0, 0);
          acc[m][n] = c;
        }
      }
    }
#pragma unroll
    for (int m = 0; m < 4; m++) {
      long rbase = row0 + wv * 64 + m * 16 + kq * 4;
#pragma unroll
      for (int n = 0; n < 7; n++) {
        int col = (g * 7 + n) * 16 + lr;
        if (col < 200) {
          float bv = bsum[col];
#pragma unroll
          for (int r = 0; r < 4; r++)
            pre[(rbase + r) * 200 + col] = acc[m][n][r] + bv;
        }
      }
    }
  }
}

// ---------------- K2: recurrence over b (256 steps); 4 waves per (t,dir) chain (round-5 proven).
template <int KO, int KN, bool OW>
__device__ __forceinline__ void rnn_loop(
    float* __restrict__ p, long step, int row, bool owns,
    const float* __restrict__ w, float (*hb)[104], float* __restrict__ ps) {
  float wr[KN];
#pragma unroll
  for (int i = 0; i < KN / 4; i++) {
    float4 w4 = *(const float4*)(w + row * HID_ + KO + 4 * i);
    wr[4 * i + 0] = w4.x; wr[4 * i + 1] = w4.y;
    wr[4 * i + 2] = w4.z; wr[4 * i + 3] = w4.w;
  }
  float a = 0.f;
  if (OW) a = p[row];
  for (int s = 0; s < B_; s++) {
    int cur = s & 1;
    float a_next = 0.f;
    if (OW && s < B_ - 1) a_next = p[step + row];
    float ac0 = OW ? a : 0.f, ac1 = 0.f, ac2 = 0.f, ac3 = 0.f;
#pragma unroll
    for (int i = 0; i < KN / 4; i++) {
      float4 h4 = *(const float4*)(&hb[cur][KO + 4 * i]);
      ac0 = fmaf(h4.x, wr[4 * i + 0], ac0);
      ac1 = fmaf(h4.y, wr[4 * i + 1], ac1);
      ac2 = fmaf(h4.z, wr[4 * i + 2], ac2);
      ac3 = fmaf(h4.w, wr[4 * i + 3], ac3);
    }
    float partial = (ac0 + ac1) + (ac2 + ac3);
    if (!OW && owns) ps[row] = partial;
    __syncthreads();
    if (OW) {
      float hnew = tanhf(partial + ps[row]);
      if (owns) {
        hb[cur ^ 1][row] = hnew;
        p[row] = hnew;
      }
    }
    p += step;
    a = a_next;
    __syncthreads();
  }
}

__global__ __launch_bounds__(256, 4) void k_rnn(
    float* __restrict__ pre,
    const float* __restrict__ whf, const float* __restrict__ whb) {
  __shared__ float hb[2][104];
  __shared__ float ps[104];
  int bid = blockIdx.x;
  int dir = bid >> 9;
  int t = bid & 511;
  const float* w = dir ? whb : whf;
  int tid = threadIdx.x;
  int wv = tid >> 6, lane = tid & 63;
  int grp = wv >> 1;
  int khalf = wv & 1;
  int row = grp ? (64 + (lane < 36 ? lane : 35)) : lane;
  bool owns = grp ? (lane < 36) : true;
  long step = dir ? -(long)(T_ * 200) : (long)(T_ * 200);
  float* p = pre + ((long)(dir ? (B_ - 1) : 0) * T_ + t) * 200 + dir * 100;
  if (tid < 104) hb[0][tid] = 0.f;
  __syncthreads();
  if (khalf == 0) rnn_loop<0, 52, true >(p, step, row, owns, w, hb, ps);
  else            rnn_loop<52, 48, false>(p, step, row, owns, w, hb, ps);
}

// ---------------- K3: logits = h @ w_lin^T + b_lin ; softmax over 19. 2 rows/thread.
__global__ __launch_bounds__(256, 4) void k_lin(
    const float* __restrict__ h, const float* __restrict__ wlin,
    const float* __restrict__ blin, float* __restrict__ em) {
  int tid = threadIdx.x;
  long r0 = ((long)blockIdx.x * 256 + tid) * 2;
  const float* h0 = h + r0 * 200;
  float acc0[K_], acc1[K_];
#pragma unroll
  for (int c = 0; c < K_; c++) { float bb = blin[c]; acc0[c] = bb; acc1[c] = bb; }
  for (int kk = 0; kk < 50; kk++) {
    float4 a = *(const float4*)(h0 + 4 * kk);
    float4 b = *(const float4*)(h0 + 200 + 4 * kk);
#pragma unroll
    for (int c = 0; c < K_; c++) {
      float4 wv = *(const float4*)(wlin + c * 200 + 4 * kk);
      acc0[c] += a.x * wv.x + a.y * wv.y + a.z * wv.z + a.w * wv.w;
      acc1[c] += b.x * wv.x + b.y * wv.y + b.z * wv.z + b.w * wv.w;
    }
  }
  float mx0 = acc0[0], mx1 = acc1[0];
#pragma unroll
  for (int c = 1; c < K_; c++) { mx0 = fmaxf(mx0, acc0[c]); mx1 = fmaxf(mx1, acc1[c]); }
  float s0 = 0.f, s1 = 0.f;
#pragma unroll
  for (int c = 0; c < K_; c++) {
    acc0[c] = __expf(acc0[c] - mx0); s0 += acc0[c];
    acc1[c] = __expf(acc1[c] - mx1); s1 += acc1[c];
  }
  float i0 = 1.f / s0, i1 = 1.f / s1;
  float* e0 = em + r0 * K_;
#pragma unroll
  for (int c = 0; c < K_; c++) { e0[c] = acc0[c] * i0; e0[K_ + c] = acc1[c] * i1; }
}

// ---------------- K4: 2 waves per b. LDS ping-pong broadcast of the 19 states
// (5x uniform ds_read_b128, no readlane hazards on the serial chain).
// wave0: logZ (lane0-shift log-space, proven) + gold score via PARALLEL gather.
// wave1: Viterbi forward + backtrack + label writes. Last block reduces loss.
__global__ __launch_bounds__(128, 1) void k_crf(
    const float* __restrict__ em, const int* __restrict__ y,
    const float* __restrict__ st_g, const float* __restrict__ en_g,
    const float* __restrict__ tr_g,
    float* __restrict__ part, int* __restrict__ cnt,
    float* __restrict__ out) {
  __shared__ __align__(16) float es[T_ * K_];
  __shared__ int ys[T_];
  __shared__ float trs[K_ * K_];
  __shared__ float st[K_], en[K_];
  __shared__ unsigned char hl[511 * K_ + 13];
  __shared__ __align__(16) float zbuf[2][20];
  __shared__ __align__(16) float vbuf[2][20];
  int b = blockIdx.x;
  int tid = threadIdx.x;
  int wv = tid >> 6, lane = tid & 63;
  const float4* eb4 = (const float4*)(em + (long)b * T_ * K_);
  for (int u = tid; u < T_ * K_ / 4; u += 128) ((float4*)es)[u] = eb4[u];
  for (int u = tid; u < T_; u += 128) ys[u] = y[b * T_ + u];
  for (int u = tid; u < K_ * K_; u += 128) trs[u] = tr_g[u];
  if (tid < K_) { st[tid] = st_g[tid]; en[tid] = en_g[tid]; }
  if (tid == 19) { zbuf[0][19] = -1e30f; zbuf[1][19] = -1e30f; vbuf[0][19] = -1e30f; vbuf[1][19] = -1e30f; }
  __syncthreads();
  // len = first masked index (mask is a prefix)
  int lmin = T_;
  for (int u = lane; u < T_; u += 64)
    if (ys[u] == -1 && u < lmin) lmin = u;
#pragma unroll
  for (int off = 32; off; off >>= 1) {
    int o = __shfl_xor(lmin, off, 64);
    lmin = lmin < o ? lmin : o;
  }
  int len = lmin;  // >= 1

  int jj = lane < K_ ? lane : K_ - 1;
  bool act = lane < K_;
  // en broadcast into lane-invariant VGPRs
  float enr[20];
#pragma unroll
  for (int q = 0; q < 5; q++) {
    float4 e4 = (q < 4) ? *(const float4*)(&en[4 * q])
                        : make_float4(en[16], en[17], en[18], -1e30f);
    enr[4 * q] = e4.x; enr[4 * q + 1] = e4.y; enr[4 * q + 2] = e4.z; enr[4 * q + 3] = e4.w;
  }

  if (wv == 0) {
    // ======== gold-path score: parallel gather over t (off the serial chain)
    float gacc = 0.f;
    for (int t = 1 + lane; t < len; t += 64)
      gacc += trs[ys[t - 1] * K_ + ys[t]] + es[t * K_ + ys[t]];
#pragma unroll
    for (int off = 32; off; off >>= 1) gacc += __shfl_xor(gacc, off, 64);
    int y0 = ys[0], ylast = ys[len - 1];
    float num = st[y0] + es[y0] + gacc + en[ylast];
    // ======== serial logZ: E column in regs; states via LDS ping-pong broadcast
    float E[K_];
#pragma unroll
    for (int i = 0; i < K_; i++) E[i] = __expf(trs[i * K_ + jj]);
    if (act) zbuf[0][lane] = st[jj] + es[jj];
    asm volatile("s_waitcnt lgkmcnt(0)" ::: "memory");
    for (int t = 1; t < len; t++) {
      int cur = (t - 1) & 1;
      float zr[20];
#pragma unroll
      for (int q = 0; q < 5; q++) {
        float4 z4 = *(const float4*)(&zbuf[cur][4 * q]);  // uniform -> broadcast
        zr[4 * q] = z4.x; zr[4 * q + 1] = z4.y; zr[4 * q + 2] = z4.z; zr[4 * q + 3] = z4.w;
      }
      float e = es[t * K_ + jj];
      float s = zr[0];
      float p0 = 1.f;  // exp(zr[0]-s)
      float a0 = p0 * E[0], a1 = 0.f, a2 = 0.f, a3 = 0.f;
#pragma unroll
      for (int i = 1; i < K_; i++) {
        float pz = __expf(zr[i] - s);
        if ((i & 3) == 1)      a1 = fmaf(pz, E[i], a1);
        else if ((i & 3) == 2) a2 = fmaf(pz, E[i], a2);
        else if ((i & 3) == 3) a3 = fmaf(pz, E[i], a3);
        else                   a0 = fmaf(pz, E[i], a0);
      }
      float nz = e + s + __logf((a0 + a1) + (a2 + a3));
      if (act) zbuf[cur ^ 1][lane] = nz;
      asm volatile("s_waitcnt lgkmcnt(0)" ::: "memory");
    }
    // final logsumexp(z + en): z in zbuf[(len-1)&1]
    {
      int cur = (len - 1) & 1;
      float zr[20];
#pragma unroll
      for (int q = 0; q < 5; q++) {
        float4 z4 = *(const float4*)(&zbuf[cur][4 * q]);
        zr[4 * q] = z4.x; zr[4 * q + 1] = z4.y; zr[4 * q + 2] = z4.z; zr[4 * q + 3] = z4.w;
      }
      float zf[K_];
#pragma unroll
      for (int i = 0; i < K_; i++) zf[i] = zr[i] + enr[i];
      float m2 = zf[0];
#pragma unroll
      for (int i = 1; i < K_; i++) m2 = fmaxf(m2, zf[i]);
      float sm = 0.f;
#pragma unroll
      for (int i = 0; i < K_; i++) sm += __expf(zf[i] - m2);
      if (lane == 0) part[b] = m2 + __logf(sm) - num;
    }
    // deterministic last-block loss reduction
    int old = -1;
    if (lane == 0) { __threadfence(); old = atomicAdd(cnt, 1); }
    old = __shfl(old, 0, 64);
    if (old == B_ - 1) {
      __threadfence();
      float s = 0.f;
      for (int u = lane; u < B_; u += 64) s += part[u];
#pragma unroll
      for (int off = 32; off; off >>= 1) s += __shfl_xor(s, off, 64);
      if (lane == 0) out[0] = s;
    }
  } else {
    // ======== Viterbi forward (column T[:,j] in regs; states via LDS ping-pong)
    float Tt[K_];
#pragma unroll
    for (int i = 0; i < K_; i++) Tt[i] = trs[i * K_ + jj];
    if (act) vbuf[0][lane] = st[jj] + es[jj];
    asm volatile("s_waitcnt lgkmcnt(0)" ::: "memory");
    for (int t = 1; t < len; t++) {
      int cur = (t - 1) & 1;
      float vr[20];
#pragma unroll
      for (int q = 0; q < 5; q++) {
        float4 v4 = *(const float4*)(&vbuf[cur][4 * q]);  // uniform -> broadcast
        vr[4 * q] = v4.x; vr[4 * q + 1] = v4.y; vr[4 * q + 2] = v4.z; vr[4 * q + 3] = v4.w;
      }
      float e = es[t * K_ + jj];
      float b0 = -1e30f, b1 = -1e30f, b2 = -1e30f, b3 = -1e30f;
      int a0 = 0, a1 = 5, a2 = 10, a3 = 15;
#pragma unroll
      for (int i = 0; i < 5; i++)  { float c = vr[i] + Tt[i]; if (c > b0) { b0 = c; a0 = i; } }
#pragma unroll
      for (int i = 5; i < 10; i++) { float c = vr[i] + Tt[i]; if (c > b1) { b1 = c; a1 = i; } }
#pragma unroll
      for (int i = 10; i < 15; i++){ float c = vr[i] + Tt[i]; if (c > b2) { b2 = c; a2 = i; } }
#pragma unroll
      for (int i = 15; i < 19; i++){ float c = vr[i] + Tt[i]; if (c > b3) { b3 = c; a3 = i; } }
      if (b1 > b0) { b0 = b1; a0 = a1; }
      if (b2 > b0) { b0 = b2; a0 = a2; }
      if (b3 > b0) { b0 = b3; a0 = a3; }
      if (act) {
        hl[(t - 1) * K_ + lane] = (unsigned char)a0;
        vbuf[cur ^ 1][lane] = b0 + e;
      }
      asm volatile("s_waitcnt lgkmcnt(0)" ::: "memory");
    }
    // final argmax (first-max) over v + en
    int aa;
    {
      int cur = (len - 1) & 1;
      float vr[20];
#pragma unroll
      for (int q = 0; q < 5; q++) {
        float4 v4 = *(const float4*)(&vbuf[cur][4 * q]);
        vr[4 * q] = v4.x; vr[4 * q + 1] = v4.y; vr[4 * q + 2] = v4.z; vr[4 * q + 3] = v4.w;
      }
      float bb = vr[0] + enr[0]; aa = 0;
#pragma unroll
      for (int i = 1; i < K_; i++) {
        float c = vr[i] + enr[i];
        if (c > bb) { bb = c; aa = i; }
      }
    }
    // backtrack + direct label writes
    float* ob = out + 1 + (long)b * T_;
    for (int u = lane; u < T_; u += 64)
      if (u >= len) ob[u] = -1.f;
    int tag = aa;
    if (lane == 0) ob[len - 1] = (float)tag;
    int vc = (act && len >= 2) ? (int)hl[(len - 2) * K_ + lane] : 0;
    for (int ti = len - 2; ti >= 0; ti--) {
      int vn = 0;
      if (ti > 0 && act) vn = (int)hl[(ti - 1) * K_ + lane];
      int ts = __builtin_amdgcn_readfirstlane(tag);
      tag = __builtin_amdgcn_readlane(vc, ts);
      if (lane == 0) ob[ti] = (float)tag;
      vc = vn;
    }
  }
}

extern "C" void kernel_launch(void* const* d_in, const int* in_sizes, int n_in,
                              void* d_out, int out_size, void* d_ws, size_t ws_size,
                              hipStream_t stream) {
  const float* x      = (const float*)d_in[0];
  const int*   y      = (const int*)d_in[1];
  const float* w_ih_f = (const float*)d_in[2];
  const float* w_hh_f = (const float*)d_in[3];
  const float* b_ih_f = (const float*)d_in[4];
  const float* b_hh_f = (const float*)d_in[5];
  const float* w_ih_b = (const float*)d_in[6];
  const float* w_hh_b = (const float*)d_in[7];
  const float* b_ih_b = (const float*)d_in[8];
  const float* b_hh_b = (const float*)d_in[9];
  const float* w_lin  = (const float*)d_in[10];
  const float* b_lin  = (const float*)d_in[11];
  const float* st     = (const float*)d_in[12];
  const float* en     = (const float*)d_in[13];
  const float* trans  = (const float*)d_in[14];

  char* ws = (char*)d_ws;
  const size_t PRE_OFF  = 0;                          // 131072*200*4 = 104857600
  const size_t EM_OFF   = 104857600;                  // 131072*19*4  = 9961472
  const size_t PART_OFF = EM_OFF + 9961472;           // 1024
  const size_t CNT_OFF  = PART_OFF + 1024;            // 4
  float* PRE  = (float*)(ws + PRE_OFF);
  float* EM   = (float*)(ws + EM_OFF);
  float* PART = (float*)(ws + PART_OFF);
  int*   CNT  = (int*)(ws + CNT_OFF);
  unsigned short* W3 = (unsigned short*)(ws + EM_OFF);  // consumed before k_lin writes EM
  float* out  = (float*)d_out;

  hipMemsetAsync((void*)CNT, 0, sizeof(int), stream);
  k_wprep<<<196, 256, 0, stream>>>(w_ih_f, w_ih_b, W3);
  k_ih<<<512, 256, 0, stream>>>(x, W3, b_ih_f, b_hh_f, b_ih_b, b_hh_b, PRE);
  k_rnn<<<1024, 256, 0, stream>>>(PRE, w_hh_f, w_hh_b);
  k_lin<<<256, 256, 0, stream>>>(PRE, w_lin, b_lin, EM);
  k_crf<<<256, 128, 0, stream>>>(EM, y, st, en, trans, PART, CNT, out);
}